// Round 1
// baseline (1121.434 us; speedup 1.0000x reference)
//
#include <hip/hip_runtime.h>
#include <math.h>

#define NN 100000     // nodes
#define NE 3200000    // edges
#define NG 64         // graphs
#define HID 16

// ---------------- workspace layout (floats) ----------------
// deg  : [0, NN)
// agg1 : [NN, 3*NN)            (N x 2)
// agg2 : [3*NN, 19*NN)         (N x 16)
// gsum : [19*NN, 19*NN+NG)
// gcnt : [19*NN+NG, 19*NN+2*NG)
// h1r  : [19*NN+2*NG, 35*NN+2*NG)   (N x 16, relu(conv1 out))
// zero region = first 19*NN + 2*NG floats

__global__ __launch_bounds__(256) void k_scatter1(
    const int* __restrict__ src, const int* __restrict__ dst,
    const float* __restrict__ x,
    float* __restrict__ deg, float* __restrict__ agg1) {
    int e = blockIdx.x * 256 + threadIdx.x;
    if (e >= NE) return;
    int s = src[e];
    int d = dst[e];
    float x0 = x[2 * s + 0];
    float x1 = x[2 * s + 1];
    unsafeAtomicAdd(&deg[d], 1.0f);
    unsafeAtomicAdd(&agg1[2 * d + 0], x0);
    unsafeAtomicAdd(&agg1[2 * d + 1], x1);
}

__global__ __launch_bounds__(256) void k_layer1(
    const float* __restrict__ x, const float* __restrict__ deg,
    const float* __restrict__ agg1,
    const float* __restrict__ W1l, const float* __restrict__ b1l,
    const float* __restrict__ W1r,
    float* __restrict__ h1r) {
    int i = blockIdx.x * 256 + threadIdx.x;
    if (i >= NN) return;
    float inv = 1.0f / fmaxf(deg[i], 1.0f);
    float a0 = agg1[2 * i + 0] * inv;
    float a1 = agg1[2 * i + 1] * inv;
    float x0 = x[2 * i + 0];
    float x1 = x[2 * i + 1];
    float out[HID];
#pragma unroll
    for (int h = 0; h < HID; ++h) {
        float v = a0 * W1l[h] + a1 * W1l[HID + h] + b1l[h]
                + x0 * W1r[h] + x1 * W1r[HID + h];
        out[h] = fmaxf(v, 0.0f);
    }
    float4* o = (float4*)(h1r + (size_t)i * HID);
#pragma unroll
    for (int q = 0; q < 4; ++q)
        o[q] = make_float4(out[4 * q + 0], out[4 * q + 1], out[4 * q + 2], out[4 * q + 3]);
}

// 4 threads per edge; each handles one float4 slice of the 16 features.
__global__ __launch_bounds__(256) void k_scatter2(
    const int* __restrict__ src, const int* __restrict__ dst,
    const float* __restrict__ h1r, float* __restrict__ agg2) {
    int gid = blockIdx.x * 256 + threadIdx.x;
    int e = gid >> 2;
    int q = gid & 3;
    if (e >= NE) return;
    int s = src[e];
    int d = dst[e];
    float4 v = *(const float4*)(h1r + (size_t)s * HID + 4 * q);
    float* p = agg2 + (size_t)d * HID + 4 * q;
    unsafeAtomicAdd(p + 0, v.x);
    unsafeAtomicAdd(p + 1, v.y);
    unsafeAtomicAdd(p + 2, v.z);
    unsafeAtomicAdd(p + 3, v.w);
}

__global__ __launch_bounds__(256) void k_layer2pool(
    const float* __restrict__ deg, const float* __restrict__ agg2,
    const float* __restrict__ h1r,
    const float* __restrict__ W2l, const float* __restrict__ b2l,
    const float* __restrict__ W2r,
    const float* __restrict__ Wend, const float* __restrict__ bend,
    const int* __restrict__ batch,
    float* __restrict__ gsum, float* __restrict__ gcnt) {
    __shared__ float sWl[256];
    __shared__ float sWr[256];
    __shared__ float sB[HID];
    __shared__ float sWe[HID];
    __shared__ float ls[NG];
    __shared__ float lc[NG];
    int t = threadIdx.x;
    sWl[t] = W2l[t];
    sWr[t] = W2r[t];
    if (t < HID) { sB[t] = b2l[t]; sWe[t] = Wend[t]; }
    if (t < NG) { ls[t] = 0.0f; lc[t] = 0.0f; }
    __syncthreads();

    int i = blockIdx.x * 256 + t;
    if (i < NN) {
        float inv = 1.0f / fmaxf(deg[i], 1.0f);
        float m[HID], hr[HID];
        const float4* pa = (const float4*)(agg2 + (size_t)i * HID);
        const float4* ph = (const float4*)(h1r + (size_t)i * HID);
#pragma unroll
        for (int q = 0; q < 4; ++q) {
            float4 a = pa[q];
            m[4 * q + 0] = a.x * inv; m[4 * q + 1] = a.y * inv;
            m[4 * q + 2] = a.z * inv; m[4 * q + 3] = a.w * inv;
            float4 hv = ph[q];
            hr[4 * q + 0] = hv.x; hr[4 * q + 1] = hv.y;
            hr[4 * q + 2] = hv.z; hr[4 * q + 3] = hv.w;
        }
        float y = bend[0];
#pragma unroll
        for (int h = 0; h < HID; ++h) {
            float acc = sB[h];
#pragma unroll
            for (int f = 0; f < HID; ++f)
                acc += m[f] * sWl[f * HID + h] + hr[f] * sWr[f * HID + h];
            y += fmaxf(acc, 0.0f) * sWe[h];
        }
        int b = batch[i];
        atomicAdd(&ls[b], y);
        atomicAdd(&lc[b], 1.0f);
    }
    __syncthreads();
    if (t < NG) {
        float c = lc[t];
        if (c != 0.0f) {
            unsafeAtomicAdd(&gsum[t], ls[t]);
            unsafeAtomicAdd(&gcnt[t], c);
        }
    }
}

__global__ void k_final(const float* __restrict__ gsum, const float* __restrict__ gcnt,
                        float* __restrict__ out) {
    int g = threadIdx.x;
    if (g < NG) {
        float p = gsum[g] / fmaxf(gcnt[g], 1.0f);
        out[g] = 1.0f / (1.0f + expf(-p));
    }
}

extern "C" void kernel_launch(void* const* d_in, const int* in_sizes, int n_in,
                              void* d_out, int out_size, void* d_ws, size_t ws_size,
                              hipStream_t stream) {
    const float* x    = (const float*)d_in[0];
    const int*   ei   = (const int*)d_in[1];
    const int*   batch= (const int*)d_in[2];
    const float* W1l  = (const float*)d_in[3];
    const float* b1l  = (const float*)d_in[4];
    const float* W1r  = (const float*)d_in[5];
    const float* W2l  = (const float*)d_in[6];
    const float* b2l  = (const float*)d_in[7];
    const float* W2r  = (const float*)d_in[8];
    const float* Wend = (const float*)d_in[9];
    const float* bend = (const float*)d_in[10];

    const int* src = ei;        // edge_index[0]
    const int* dst = ei + NE;   // edge_index[1]

    float* ws   = (float*)d_ws;
    float* deg  = ws;
    float* agg1 = ws + (size_t)NN;
    float* agg2 = ws + (size_t)3 * NN;
    float* gsum = ws + (size_t)19 * NN;
    float* gcnt = ws + (size_t)19 * NN + NG;
    float* h1r  = ws + (size_t)19 * NN + 2 * NG;

    // zero accumulators (harness poisons ws with 0xAA; no re-poison between replays)
    hipMemsetAsync(d_ws, 0, ((size_t)19 * NN + 2 * NG) * sizeof(float), stream);

    k_scatter1<<<(NE + 255) / 256, 256, 0, stream>>>(src, dst, x, deg, agg1);
    k_layer1<<<(NN + 255) / 256, 256, 0, stream>>>(x, deg, agg1, W1l, b1l, W1r, h1r);
    k_scatter2<<<(4 * NE + 255) / 256, 256, 0, stream>>>(src, dst, h1r, agg2);
    k_layer2pool<<<(NN + 255) / 256, 256, 0, stream>>>(deg, agg2, h1r, W2l, b2l, W2r,
                                                       Wend, bend, batch, gsum, gcnt);
    k_final<<<1, 64, 0, stream>>>(gsum, gcnt, (float*)d_out);
}

// Round 2
// 572.683 us; speedup vs baseline: 1.9582x; 1.9582x over previous
//
#include <hip/hip_runtime.h>
#include <math.h>

#define NN 100000     // nodes
#define NE 3200000    // edges
#define NG 64         // graphs
#define HID 16
#define NBLK ((NN + 255) / 256)   // 391 blocks over nodes

// ---------------- workspace layout (4-byte units) ----------------
// cnt    [0, NN)              int   (in-degree)          } zeroed
// gsum   [NN, NN+NG)          float                      } zeroed
// gcnt   [NN+NG, NN+2NG)      float                      } zeroed
// offs   [NN+2NG, 2NN+2NG)    int   (CSR row starts)
// cursor [2NN+2NG, 3NN+2NG)   int   (fill cursors)
// partial[3NN+2NG, +512)      int   (block partial sums)
// csr    [.., +NE)            int   (src ids grouped by dst)
// h1r    [.., +16NN)          float (relu(conv1 out))

__global__ __launch_bounds__(256) void k_hist(const int* __restrict__ dst,
                                              int* __restrict__ cnt) {
    int e = blockIdx.x * 256 + threadIdx.x;
    if (e < NE) atomicAdd(&cnt[dst[e]], 1);
}

__global__ __launch_bounds__(256) void k_blocksum(const int* __restrict__ cnt,
                                                  int* __restrict__ partial) {
    __shared__ int s[256];
    int i = blockIdx.x * 256 + threadIdx.x;
    s[threadIdx.x] = (i < NN) ? cnt[i] : 0;
    __syncthreads();
    for (int off = 128; off > 0; off >>= 1) {
        if (threadIdx.x < off) s[threadIdx.x] += s[threadIdx.x + off];
        __syncthreads();
    }
    if (threadIdx.x == 0) partial[blockIdx.x] = s[0];
}

__global__ __launch_bounds__(512) void k_scanpartial(int* __restrict__ partial) {
    __shared__ int s[NBLK];
    int t = threadIdx.x;
    if (t < NBLK) s[t] = partial[t];
    __syncthreads();
    if (t == 0) {
        int run = 0;
        for (int i = 0; i < NBLK; ++i) { int v = s[i]; s[i] = run; run += v; }
    }
    __syncthreads();
    if (t < NBLK) partial[t] = s[t];
}

__global__ __launch_bounds__(256) void k_offsets(const int* __restrict__ cnt,
                                                 const int* __restrict__ partial,
                                                 int* __restrict__ offs,
                                                 int* __restrict__ cursor) {
    __shared__ int s[256];
    int i = blockIdx.x * 256 + threadIdx.x;
    s[threadIdx.x] = (i < NN) ? cnt[i] : 0;
    __syncthreads();
    if (threadIdx.x == 0) {
        int run = partial[blockIdx.x];
        for (int k = 0; k < 256; ++k) { int v = s[k]; s[k] = run; run += v; }
    }
    __syncthreads();
    if (i < NN) { offs[i] = s[threadIdx.x]; cursor[i] = s[threadIdx.x]; }
}

__global__ __launch_bounds__(256) void k_fill(const int* __restrict__ src,
                                              const int* __restrict__ dst,
                                              int* __restrict__ cursor,
                                              int* __restrict__ csr) {
    int e = blockIdx.x * 256 + threadIdx.x;
    if (e < NE) {
        int d = dst[e];
        int pos = atomicAdd(&cursor[d], 1);
        csr[pos] = src[e];
    }
}

// conv1 via CSR gather (2 features), GEMV 2->16, relu, store h1r.
__global__ __launch_bounds__(256) void k_layer1g(
    const int* __restrict__ offs, const int* __restrict__ cnt,
    const int* __restrict__ csr, const float* __restrict__ x,
    const float* __restrict__ W1l, const float* __restrict__ b1l,
    const float* __restrict__ W1r, float* __restrict__ h1r) {
    int i = blockIdx.x * 256 + threadIdx.x;
    if (i >= NN) return;
    int beg = offs[i], c = cnt[i];
    float s0 = 0.0f, s1 = 0.0f;
    for (int k = 0; k < c; ++k) {
        int s = csr[beg + k];
        float2 xv = *(const float2*)(x + 2 * s);
        s0 += xv.x; s1 += xv.y;
    }
    float inv = 1.0f / fmaxf((float)c, 1.0f);
    float a0 = s0 * inv, a1 = s1 * inv;
    float x0 = x[2 * i + 0], x1 = x[2 * i + 1];
    float out[HID];
#pragma unroll
    for (int h = 0; h < HID; ++h) {
        float v = a0 * W1l[h] + a1 * W1l[HID + h] + b1l[h]
                + x0 * W1r[h] + x1 * W1r[HID + h];
        out[h] = fmaxf(v, 0.0f);
    }
    float4* o = (float4*)(h1r + (size_t)i * HID);
#pragma unroll
    for (int q = 0; q < 4; ++q)
        o[q] = make_float4(out[4 * q + 0], out[4 * q + 1], out[4 * q + 2], out[4 * q + 3]);
}

// conv2 gather (16 thr/node, coalesced 64B per neighbor) + GEMV + head + pool.
__global__ __launch_bounds__(256) void k_conv2pool(
    const int* __restrict__ offs, const int* __restrict__ cnt,
    const int* __restrict__ csr, const float* __restrict__ h1r,
    const float* __restrict__ W2l, const float* __restrict__ b2l,
    const float* __restrict__ W2r, const float* __restrict__ Wend,
    const float* __restrict__ bend, const int* __restrict__ batch,
    float* __restrict__ gsum, float* __restrict__ gcnt) {
    __shared__ float sWl[256], sWr[256], sB[HID], sWe[HID];
    __shared__ float sm[16][17], shr[16][17];
    __shared__ float ls[NG], lc[NG];
    int t = threadIdx.x;
    sWl[t] = W2l[t];
    sWr[t] = W2r[t];
    if (t < HID) { sB[t] = b2l[t]; sWe[t] = Wend[t]; }
    if (t < NG) { ls[t] = 0.0f; lc[t] = 0.0f; }

    int g = t >> 4, f = t & 15;
    int i = blockIdx.x * 16 + g;           // 6250*16 == NN exactly
    int beg = offs[i], c = cnt[i];
    float acc = 0.0f;
    for (int k = 0; k < c; ++k) {
        int s = csr[beg + k];              // broadcast across the 16 lanes
        acc += h1r[(size_t)s * HID + f];   // coalesced 64B line
    }
    float inv = 1.0f / fmaxf((float)c, 1.0f);
    sm[g][f] = acc * inv;
    shr[g][f] = h1r[(size_t)i * HID + f];
    __syncthreads();

    int h = f;
    float a = sB[h];
#pragma unroll
    for (int ff = 0; ff < HID; ++ff)
        a += sm[g][ff] * sWl[ff * HID + h] + shr[g][ff] * sWr[ff * HID + h];
    float y = fmaxf(a, 0.0f) * sWe[h];
    // sum the 16 per-h contributions within the contiguous 16-lane group
    y += __shfl_xor(y, 1, 64);
    y += __shfl_xor(y, 2, 64);
    y += __shfl_xor(y, 4, 64);
    y += __shfl_xor(y, 8, 64);
    if (f == 0) {
        y += bend[0];
        int b = batch[i];
        atomicAdd(&ls[b], y);
        atomicAdd(&lc[b], 1.0f);
    }
    __syncthreads();
    if (t < NG && lc[t] != 0.0f) {
        unsafeAtomicAdd(&gsum[t], ls[t]);
        unsafeAtomicAdd(&gcnt[t], lc[t]);
    }
}

__global__ void k_final(const float* __restrict__ gsum, const float* __restrict__ gcnt,
                        float* __restrict__ out) {
    int g = threadIdx.x;
    if (g < NG) {
        float p = gsum[g] / fmaxf(gcnt[g], 1.0f);
        out[g] = 1.0f / (1.0f + expf(-p));
    }
}

extern "C" void kernel_launch(void* const* d_in, const int* in_sizes, int n_in,
                              void* d_out, int out_size, void* d_ws, size_t ws_size,
                              hipStream_t stream) {
    const float* x    = (const float*)d_in[0];
    const int*   ei   = (const int*)d_in[1];
    const int*   batch= (const int*)d_in[2];
    const float* W1l  = (const float*)d_in[3];
    const float* b1l  = (const float*)d_in[4];
    const float* W1r  = (const float*)d_in[5];
    const float* W2l  = (const float*)d_in[6];
    const float* b2l  = (const float*)d_in[7];
    const float* W2r  = (const float*)d_in[8];
    const float* Wend = (const float*)d_in[9];
    const float* bend = (const float*)d_in[10];

    const int* src = ei;        // edge_index[0]
    const int* dst = ei + NE;   // edge_index[1]

    int*   cnt     = (int*)d_ws;
    float* gsum    = (float*)d_ws + NN;
    float* gcnt    = (float*)d_ws + NN + NG;
    int*   offs    = (int*)d_ws + NN + 2 * NG;
    int*   cursor  = (int*)d_ws + 2 * NN + 2 * NG;
    int*   partial = (int*)d_ws + 3 * NN + 2 * NG;
    int*   csr     = (int*)d_ws + 3 * NN + 2 * NG + 512;
    float* h1r     = (float*)d_ws + (size_t)3 * NN + 2 * NG + 512 + NE;

    // zero cnt + gsum + gcnt (ws is NOT re-poisoned between timed replays)
    hipMemsetAsync(d_ws, 0, (size_t)(NN + 2 * NG) * sizeof(float), stream);

    k_hist       <<<(NE + 255) / 256, 256, 0, stream>>>(dst, cnt);
    k_blocksum   <<<NBLK, 256, 0, stream>>>(cnt, partial);
    k_scanpartial<<<1, 512, 0, stream>>>(partial);
    k_offsets    <<<NBLK, 256, 0, stream>>>(cnt, partial, offs, cursor);
    k_fill       <<<(NE + 255) / 256, 256, 0, stream>>>(src, dst, cursor, csr);
    k_layer1g    <<<(NN + 255) / 256, 256, 0, stream>>>(offs, cnt, csr, x, W1l, b1l, W1r, h1r);
    k_conv2pool  <<<NN / 16, 256, 0, stream>>>(offs, cnt, csr, h1r, W2l, b2l, W2r,
                                               Wend, bend, batch, gsum, gcnt);
    k_final      <<<1, 64, 0, stream>>>(gsum, gcnt, (float*)d_out);
}

// Round 3
// 239.903 us; speedup vs baseline: 4.6745x; 2.3871x over previous
//
#include <hip/hip_runtime.h>
#include <math.h>

#define NN 100000     // nodes
#define NE 3200000    // edges
#define NG 64         // graphs
#define HID 16
#define EPB 8192                          // edges per block in bucket pipeline
#define NBLKE ((NE + EPB - 1) / EPB)      // 391 edge blocks
#define NBUCK ((NN + 255) / 256)          // 391 buckets (256 nodes each)

// ---------------- workspace layout (4-byte units) ----------------
// gsum      [0, NG)                     float  } zeroed each launch
// gcnt      [NG, 2NG)                   float  } zeroed each launch
// blockCnt  [2NG, +NBLKE*NBUCK)         int    (layout [blk][bucket]; becomes per-block excl prefix)
// bucketTot [.., +NBUCK)                int
// bucketBase[.., +NBUCK+1)              int
// offs      [.., +NN+1)                 int    (node CSR offsets)
// pairs     [.., +NE)                   int    ((src<<8)|dst_low8, bucket-sorted)
// csr       [.., +NE)                   int    (src ids grouped by dst)
// h1r       [.., +16NN)                 float

// per-block bucket histogram
__global__ __launch_bounds__(256) void k_bhist(const int* __restrict__ dst,
                                               int* __restrict__ blockCnt) {
    __shared__ int h[NBUCK];
    int t = threadIdx.x;
    for (int i = t; i < NBUCK; i += 256) h[i] = 0;
    __syncthreads();
    int base = blockIdx.x * EPB;
    int end = min(base + EPB, NE);
    for (int e = base + t; e < end; e += 256)
        atomicAdd(&h[dst[e] >> 8], 1);
    __syncthreads();
    for (int i = t; i < NBUCK; i += 256)
        blockCnt[blockIdx.x * NBUCK + i] = h[i];   // coalesced
}

// per-bucket: exclusive prefix over the 391 edge-blocks (in place) + bucket total
__global__ __launch_bounds__(512) void k_bucketscan(int* __restrict__ blockCnt,
                                                    int* __restrict__ bucketTot) {
    __shared__ int a[512];
    int t = threadIdx.x, b = blockIdx.x;
    a[t] = (t < NBLKE) ? blockCnt[t * NBUCK + b] : 0;
    __syncthreads();
    for (int off = 1; off < 512; off <<= 1) {
        int x = a[t] + ((t >= off) ? a[t - off] : 0);
        __syncthreads();
        a[t] = x;
        __syncthreads();
    }
    if (t < NBLKE) blockCnt[t * NBUCK + b] = (t ? a[t - 1] : 0);
    if (t == 0) bucketTot[b] = a[511];
}

// exclusive scan of bucket totals -> bucketBase; sentinel offs[NN]=NE
__global__ __launch_bounds__(512) void k_basescan(const int* __restrict__ bucketTot,
                                                  int* __restrict__ bucketBase,
                                                  int* __restrict__ offs) {
    __shared__ int a[512];
    int t = threadIdx.x;
    a[t] = (t < NBUCK) ? bucketTot[t] : 0;
    __syncthreads();
    for (int off = 1; off < 512; off <<= 1) {
        int x = a[t] + ((t >= off) ? a[t - off] : 0);
        __syncthreads();
        a[t] = x;
        __syncthreads();
    }
    if (t < NBUCK) bucketBase[t] = (t ? a[t - 1] : 0);
    if (t == 0) { bucketBase[NBUCK] = a[511]; offs[NN] = a[511]; }
}

// scatter packed (src<<8 | dst&255) into bucket-partitioned pairs array
__global__ __launch_bounds__(256) void k_bscatter(const int* __restrict__ src,
                                                  const int* __restrict__ dst,
                                                  const int* __restrict__ blockCnt,
                                                  const int* __restrict__ bucketBase,
                                                  int* __restrict__ pairs) {
    __shared__ int cur[NBUCK];
    int t = threadIdx.x;
    for (int i = t; i < NBUCK; i += 256)
        cur[i] = blockCnt[blockIdx.x * NBUCK + i] + bucketBase[i];
    __syncthreads();
    int base = blockIdx.x * EPB;
    int end = min(base + EPB, NE);
    for (int e = base + t; e < end; e += 256) {
        int d = dst[e];
        int pos = atomicAdd(&cur[d >> 8], 1);
        pairs[pos] = (src[e] << 8) | (d & 255);
    }
}

// one block per bucket: local node histogram + scan -> offs, then csr fill
__global__ __launch_bounds__(256) void k_fill2(const int* __restrict__ bucketBase,
                                               const int* __restrict__ pairs,
                                               int* __restrict__ offs,
                                               int* __restrict__ csr) {
    __shared__ int a[256];
    __shared__ int lcur[256];
    int t = threadIdx.x, b = blockIdx.x;
    int pb = bucketBase[b], pe = bucketBase[b + 1];
    a[t] = 0;
    __syncthreads();
    for (int e = pb + t; e < pe; e += 256)
        atomicAdd(&a[pairs[e] & 255], 1);
    __syncthreads();
    for (int off = 1; off < 256; off <<= 1) {
        int x = a[t] + ((t >= off) ? a[t - off] : 0);
        __syncthreads();
        a[t] = x;
        __syncthreads();
    }
    int excl = t ? a[t - 1] : 0;
    int node = b * 256 + t;
    if (node < NN) offs[node] = pb + excl;
    lcur[t] = pb + excl;
    __syncthreads();
    for (int e = pb + t; e < pe; e += 256) {
        int v = pairs[e];
        int pos = atomicAdd(&lcur[v & 255], 1);
        csr[pos] = v >> 8;
    }
}

// conv1 via CSR gather (2 features), GEMV 2->16, relu, store h1r.
__global__ __launch_bounds__(256) void k_layer1g(
    const int* __restrict__ offs, const int* __restrict__ csr,
    const float* __restrict__ x,
    const float* __restrict__ W1l, const float* __restrict__ b1l,
    const float* __restrict__ W1r, float* __restrict__ h1r) {
    int i = blockIdx.x * 256 + threadIdx.x;
    if (i >= NN) return;
    int beg = offs[i], c = offs[i + 1] - beg;
    float s0 = 0.0f, s1 = 0.0f;
    for (int k = 0; k < c; ++k) {
        int s = csr[beg + k];
        float2 xv = *(const float2*)(x + 2 * s);
        s0 += xv.x; s1 += xv.y;
    }
    float inv = 1.0f / fmaxf((float)c, 1.0f);
    float a0 = s0 * inv, a1 = s1 * inv;
    float x0 = x[2 * i + 0], x1 = x[2 * i + 1];
    float out[HID];
#pragma unroll
    for (int h = 0; h < HID; ++h) {
        float v = a0 * W1l[h] + a1 * W1l[HID + h] + b1l[h]
                + x0 * W1r[h] + x1 * W1r[HID + h];
        out[h] = fmaxf(v, 0.0f);
    }
    float4* o = (float4*)(h1r + (size_t)i * HID);
#pragma unroll
    for (int q = 0; q < 4; ++q)
        o[q] = make_float4(out[4 * q + 0], out[4 * q + 1], out[4 * q + 2], out[4 * q + 3]);
}

// conv2 gather (16 thr/node, coalesced 64B per neighbor) + GEMV + head + pool.
__global__ __launch_bounds__(256) void k_conv2pool(
    const int* __restrict__ offs, const int* __restrict__ csr,
    const float* __restrict__ h1r,
    const float* __restrict__ W2l, const float* __restrict__ b2l,
    const float* __restrict__ W2r, const float* __restrict__ Wend,
    const float* __restrict__ bend, const int* __restrict__ batch,
    float* __restrict__ gsum, float* __restrict__ gcnt) {
    __shared__ float sWl[256], sWr[256], sB[HID], sWe[HID];
    __shared__ float sm[16][17], shr[16][17];
    __shared__ float ls[NG], lc[NG];
    int t = threadIdx.x;
    sWl[t] = W2l[t];
    sWr[t] = W2r[t];
    if (t < HID) { sB[t] = b2l[t]; sWe[t] = Wend[t]; }
    if (t < NG) { ls[t] = 0.0f; lc[t] = 0.0f; }

    int g = t >> 4, f = t & 15;
    int i = blockIdx.x * 16 + g;           // 6250*16 == NN exactly
    int beg = offs[i], c = offs[i + 1] - beg;
    float acc = 0.0f;
    for (int k = 0; k < c; ++k) {
        int s = csr[beg + k];              // broadcast across the 16 lanes
        acc += h1r[(size_t)s * HID + f];   // coalesced 64B line
    }
    float inv = 1.0f / fmaxf((float)c, 1.0f);
    sm[g][f] = acc * inv;
    shr[g][f] = h1r[(size_t)i * HID + f];
    __syncthreads();

    int h = f;
    float a = sB[h];
#pragma unroll
    for (int ff = 0; ff < HID; ++ff)
        a += sm[g][ff] * sWl[ff * HID + h] + shr[g][ff] * sWr[ff * HID + h];
    float y = fmaxf(a, 0.0f) * sWe[h];
    y += __shfl_xor(y, 1, 64);
    y += __shfl_xor(y, 2, 64);
    y += __shfl_xor(y, 4, 64);
    y += __shfl_xor(y, 8, 64);
    if (f == 0) {
        y += bend[0];
        int b = batch[i];
        atomicAdd(&ls[b], y);
        atomicAdd(&lc[b], 1.0f);
    }
    __syncthreads();
    if (t < NG && lc[t] != 0.0f) {
        unsafeAtomicAdd(&gsum[t], ls[t]);
        unsafeAtomicAdd(&gcnt[t], lc[t]);
    }
}

__global__ void k_final(const float* __restrict__ gsum, const float* __restrict__ gcnt,
                        float* __restrict__ out) {
    int g = threadIdx.x;
    if (g < NG) {
        float p = gsum[g] / fmaxf(gcnt[g], 1.0f);
        out[g] = 1.0f / (1.0f + expf(-p));
    }
}

extern "C" void kernel_launch(void* const* d_in, const int* in_sizes, int n_in,
                              void* d_out, int out_size, void* d_ws, size_t ws_size,
                              hipStream_t stream) {
    const float* x    = (const float*)d_in[0];
    const int*   ei   = (const int*)d_in[1];
    const int*   batch= (const int*)d_in[2];
    const float* W1l  = (const float*)d_in[3];
    const float* b1l  = (const float*)d_in[4];
    const float* W1r  = (const float*)d_in[5];
    const float* W2l  = (const float*)d_in[6];
    const float* b2l  = (const float*)d_in[7];
    const float* W2r  = (const float*)d_in[8];
    const float* Wend = (const float*)d_in[9];
    const float* bend = (const float*)d_in[10];

    const int* src = ei;        // edge_index[0]
    const int* dst = ei + NE;   // edge_index[1]

    float* ws        = (float*)d_ws;
    float* gsum      = ws;
    float* gcnt      = ws + NG;
    int*   blockCnt  = (int*)d_ws + 2 * NG;
    int*   bucketTot = blockCnt + (size_t)NBLKE * NBUCK;
    int*   bucketBase= bucketTot + NBUCK;
    int*   offs      = bucketBase + NBUCK + 1;
    int*   pairs     = offs + NN + 1;
    int*   csr       = pairs + NE;
    float* h1r       = (float*)(csr + NE);

    // zero only gsum/gcnt (everything else is fully rewritten each launch)
    hipMemsetAsync(d_ws, 0, 2 * NG * sizeof(float), stream);

    k_bhist     <<<NBLKE, 256, 0, stream>>>(dst, blockCnt);
    k_bucketscan<<<NBUCK, 512, 0, stream>>>(blockCnt, bucketTot);
    k_basescan  <<<1, 512, 0, stream>>>(bucketTot, bucketBase, offs);
    k_bscatter  <<<NBLKE, 256, 0, stream>>>(src, dst, blockCnt, bucketBase, pairs);
    k_fill2     <<<NBUCK, 256, 0, stream>>>(bucketBase, pairs, offs, csr);
    k_layer1g   <<<(NN + 255) / 256, 256, 0, stream>>>(offs, csr, x, W1l, b1l, W1r, h1r);
    k_conv2pool <<<NN / 16, 256, 0, stream>>>(offs, csr, h1r, W2l, b2l, W2r,
                                              Wend, bend, batch, gsum, gcnt);
    k_final     <<<1, 64, 0, stream>>>(gsum, gcnt, (float*)d_out);
}

// Round 4
// 144.318 us; speedup vs baseline: 7.7706x; 1.6623x over previous
//
#include <hip/hip_runtime.h>
#include <math.h>

#define NN 100000     // nodes
#define NE 3200000    // edges
#define NG 64         // graphs
#define HID 16
#define EPB 8192                          // edges per block in bucket pipeline
#define NBLKE ((NE + EPB - 1) / EPB)      // 391 edge blocks
#define NBUCK ((NN + 255) / 256)          // 391 buckets (256 nodes each)

typedef unsigned int uint;

// ---------------- workspace layout (4-byte units) ----------------
// gsum      [0, NG)                     float  } zeroed each launch
// gcnt      [NG, 2NG)                   float  } zeroed each launch
// blockCnt  [2NG, +NBLKE*NBUCK)         int
// bucketTot [.., +NBUCK)                int
// bucketBase[.., +NBUCK+1)              int
// offs      [.., +NN+1)                 int    (node CSR offsets; [NN]=NE sentinel)
// pad to 16B
// pairs     [.., +NE)                   int    ((src<<8)|dst_low8, bucket-sorted)
// csr       [.., +NE)                   int    (src ids grouped by dst)
// h1u       [.., +8*NN)                 uint   (h1 relu'd, bf16x2 packed, 32B/row)

__device__ inline uint bf16pair(float a, float b) {
    uint ua = __float_as_uint(a), ub = __float_as_uint(b);
    ua = (ua + 0x7fffu + ((ua >> 16) & 1u)) >> 16;
    ub = (ub + 0x7fffu + ((ub >> 16) & 1u)) >> 16;
    return ua | (ub << 16);
}

__global__ __launch_bounds__(512) void k_bhist(const int* __restrict__ dst,
                                               int* __restrict__ blockCnt) {
    __shared__ int h[NBUCK];
    int t = threadIdx.x;
    for (int i = t; i < NBUCK; i += 512) h[i] = 0;
    __syncthreads();
    int base = blockIdx.x * EPB;
    int end = min(base + EPB, NE);
    for (int e = base + t; e < end; e += 512)
        atomicAdd(&h[dst[e] >> 8], 1);
    __syncthreads();
    for (int i = t; i < NBUCK; i += 512)
        blockCnt[blockIdx.x * NBUCK + i] = h[i];
}

// per-bucket: exclusive prefix over the 391 edge-blocks (in place) + bucket total
__global__ __launch_bounds__(512) void k_bucketscan(int* __restrict__ blockCnt,
                                                    int* __restrict__ bucketTot) {
    __shared__ int a[512];
    int t = threadIdx.x, b = blockIdx.x;
    a[t] = (t < NBLKE) ? blockCnt[t * NBUCK + b] : 0;
    __syncthreads();
    for (int off = 1; off < 512; off <<= 1) {
        int x = a[t] + ((t >= off) ? a[t - off] : 0);
        __syncthreads();
        a[t] = x;
        __syncthreads();
    }
    if (t < NBLKE) blockCnt[t * NBUCK + b] = (t ? a[t - 1] : 0);
    if (t == 0) bucketTot[b] = a[511];
}

// exclusive scan of bucket totals -> bucketBase; sentinel offs[NN]=NE
__global__ __launch_bounds__(512) void k_basescan(const int* __restrict__ bucketTot,
                                                  int* __restrict__ bucketBase,
                                                  int* __restrict__ offs) {
    __shared__ int a[512];
    int t = threadIdx.x;
    a[t] = (t < NBUCK) ? bucketTot[t] : 0;
    __syncthreads();
    for (int off = 1; off < 512; off <<= 1) {
        int x = a[t] + ((t >= off) ? a[t - off] : 0);
        __syncthreads();
        a[t] = x;
        __syncthreads();
    }
    if (t < NBUCK) bucketBase[t] = (t ? a[t - 1] : 0);
    if (t == 0) { bucketBase[NBUCK] = a[511]; offs[NN] = a[511]; }
}

// scatter packed (src<<8 | dst&255) into bucket-partitioned pairs array
__global__ __launch_bounds__(512) void k_bscatter(const int* __restrict__ src,
                                                  const int* __restrict__ dst,
                                                  const int* __restrict__ blockCnt,
                                                  const int* __restrict__ bucketBase,
                                                  int* __restrict__ pairs) {
    __shared__ int cur[NBUCK];
    int t = threadIdx.x;
    for (int i = t; i < NBUCK; i += 512)
        cur[i] = blockCnt[blockIdx.x * NBUCK + i] + bucketBase[i];
    __syncthreads();
    int base = blockIdx.x * EPB;
    int end = min(base + EPB, NE);
    for (int e = base + t; e < end; e += 512) {
        int d = dst[e];
        int pos = atomicAdd(&cur[d >> 8], 1);
        pairs[pos] = (src[e] << 8) | (d & 255);
    }
}

// one block per bucket: node hist+scan -> offs; csr fill; fused conv1
// (edge-parallel LDS x-accumulation + per-node 2->16 GEMV, relu, bf16 store)
__global__ __launch_bounds__(512) void k_fill2c1(
    const int* __restrict__ bucketBase, const int* __restrict__ pairs,
    const float* __restrict__ x,
    const float* __restrict__ W1l, const float* __restrict__ b1l,
    const float* __restrict__ W1r,
    int* __restrict__ offs, int* __restrict__ csr, uint* __restrict__ h1u) {
    __shared__ int a[256];
    __shared__ int lcur[256];
    __shared__ float xs0[256], xs1[256];
    int t = threadIdx.x, b = blockIdx.x;
    int pb = bucketBase[b], pe = bucketBase[b + 1];
    if (t < 256) { a[t] = 0; xs0[t] = 0.f; xs1[t] = 0.f; }
    __syncthreads();
    for (int e = pb + t; e < pe; e += 512)
        atomicAdd(&a[pairs[e] & 255], 1);
    __syncthreads();
    for (int off = 1; off < 256; off <<= 1) {
        int v = 0;
        if (t < 256) v = a[t] + ((t >= off) ? a[t - off] : 0);
        __syncthreads();
        if (t < 256) a[t] = v;
        __syncthreads();
    }
    if (t < 256) {
        int excl = t ? a[t - 1] : 0;
        int node = b * 256 + t;
        if (node < NN) offs[node] = pb + excl;
        lcur[t] = pb + excl;
    }
    __syncthreads();
    for (int e = pb + t; e < pe; e += 512) {
        int v = pairs[e];
        int s = v >> 8, dl = v & 255;
        int pos = atomicAdd(&lcur[dl], 1);
        csr[pos] = s;
        float2 xv = *(const float2*)(x + 2 * s);
        atomicAdd(&xs0[dl], xv.x);
        atomicAdd(&xs1[dl], xv.y);
    }
    __syncthreads();
    if (t < 256) {
        int node = b * 256 + t;
        if (node < NN) {
            int excl = t ? a[t - 1] : 0;
            int cntn = a[t] - excl;
            float inv = 1.0f / fmaxf((float)cntn, 1.0f);
            float m0 = xs0[t] * inv, m1 = xs1[t] * inv;
            float x0 = x[2 * node], x1 = x[2 * node + 1];
            float o[16];
#pragma unroll
            for (int h = 0; h < 16; ++h)
                o[h] = fmaxf(m0 * W1l[h] + m1 * W1l[16 + h] + b1l[h]
                           + x0 * W1r[h] + x1 * W1r[16 + h], 0.f);
            uint4 o0, o1;
            o0.x = bf16pair(o[0], o[1]);   o0.y = bf16pair(o[2], o[3]);
            o0.z = bf16pair(o[4], o[5]);   o0.w = bf16pair(o[6], o[7]);
            o1.x = bf16pair(o[8], o[9]);   o1.y = bf16pair(o[10], o[11]);
            o1.z = bf16pair(o[12], o[13]); o1.w = bf16pair(o[14], o[15]);
            uint4* d4 = (uint4*)(h1u + (size_t)node * 8);
            d4[0] = o0; d4[1] = o1;
        }
    }
}

// conv2 + head + pool. 8 lanes/node, 32 nodes/block.
// csr entries batch-loaded 8 at a time and shfl-broadcast -> 8 independent
// 32B bf16 row gathers in flight per group (64 per wave).
__global__ __launch_bounds__(256) void k_conv2pool(
    const int* __restrict__ offs, const int* __restrict__ csr,
    const uint* __restrict__ h1u,
    const float* __restrict__ W2l, const float* __restrict__ b2l,
    const float* __restrict__ W2r, const float* __restrict__ Wend,
    const float* __restrict__ bend, const int* __restrict__ batch,
    float* __restrict__ gsum, float* __restrict__ gcnt) {
    __shared__ float sWl[256], sWr[256], sB[HID], sWe[HID];
    __shared__ float sm[32][17], shr[32][17];
    __shared__ float ls[NG], lc[NG];
    int t = threadIdx.x;
    sWl[t] = W2l[t];
    sWr[t] = W2r[t];
    if (t < HID) { sB[t] = b2l[t]; sWe[t] = Wend[t]; }
    if (t < NG) { ls[t] = 0.f; lc[t] = 0.f; }

    int g = t >> 3;              // node slot 0..31
    int l8 = t & 7;
    int gbase = (t & 63) & 56;   // wave-relative base lane of 8-lane group
    int i = blockIdx.x * 32 + g; // 3125*32 == NN exactly
    int beg = offs[i], end = offs[i + 1];
    float acc0 = 0.f, acc1 = 0.f;
    int kb = beg;
    for (; kb + 8 <= end; kb += 8) {
        int sv = csr[kb + l8];
#pragma unroll
        for (int j = 0; j < 8; ++j) {
            int s = __shfl(sv, gbase + j, 64);
            uint u = h1u[(size_t)s * 8 + l8];
            acc0 += __uint_as_float(u << 16);
            acc1 += __uint_as_float(u & 0xffff0000u);
        }
    }
    if (kb < end) {
        int idx = kb + l8;
        int sv = (idx < end) ? csr[idx] : 0;
        int nb = end - kb;
        for (int j = 0; j < nb; ++j) {
            int s = __shfl(sv, gbase + j, 64);
            uint u = h1u[(size_t)s * 8 + l8];
            acc0 += __uint_as_float(u << 16);
            acc1 += __uint_as_float(u & 0xffff0000u);
        }
    }
    float inv = 1.0f / fmaxf((float)(end - beg), 1.0f);
    uint us = h1u[(size_t)i * 8 + l8];
    sm[g][2 * l8]     = acc0 * inv;
    sm[g][2 * l8 + 1] = acc1 * inv;
    shr[g][2 * l8]     = __uint_as_float(us << 16);
    shr[g][2 * l8 + 1] = __uint_as_float(us & 0xffff0000u);
    __syncthreads();

    // GEMV: each thread computes outputs h=l8 and h=l8+8 for node g
    int h0 = l8, h1 = l8 + 8;
    float a0 = sB[h0], a1 = sB[h1];
#pragma unroll
    for (int ff = 0; ff < HID; ++ff) {
        float m = sm[g][ff], r = shr[g][ff];
        a0 += m * sWl[ff * HID + h0] + r * sWr[ff * HID + h0];
        a1 += m * sWl[ff * HID + h1] + r * sWr[ff * HID + h1];
    }
    float y = fmaxf(a0, 0.f) * sWe[h0] + fmaxf(a1, 0.f) * sWe[h1];
    y += __shfl_xor(y, 1, 64);
    y += __shfl_xor(y, 2, 64);
    y += __shfl_xor(y, 4, 64);
    if (l8 == 0) {
        int bg = batch[i];
        atomicAdd(&ls[bg], y + bend[0]);
        atomicAdd(&lc[bg], 1.0f);
    }
    __syncthreads();
    if (t < NG && lc[t] != 0.0f) {
        unsafeAtomicAdd(&gsum[t], ls[t]);
        unsafeAtomicAdd(&gcnt[t], lc[t]);
    }
}

__global__ void k_final(const float* __restrict__ gsum, const float* __restrict__ gcnt,
                        float* __restrict__ out) {
    int g = threadIdx.x;
    if (g < NG) {
        float p = gsum[g] / fmaxf(gcnt[g], 1.0f);
        out[g] = 1.0f / (1.0f + expf(-p));
    }
}

extern "C" void kernel_launch(void* const* d_in, const int* in_sizes, int n_in,
                              void* d_out, int out_size, void* d_ws, size_t ws_size,
                              hipStream_t stream) {
    const float* x    = (const float*)d_in[0];
    const int*   ei   = (const int*)d_in[1];
    const int*   batch= (const int*)d_in[2];
    const float* W1l  = (const float*)d_in[3];
    const float* b1l  = (const float*)d_in[4];
    const float* W1r  = (const float*)d_in[5];
    const float* W2l  = (const float*)d_in[6];
    const float* b2l  = (const float*)d_in[7];
    const float* W2r  = (const float*)d_in[8];
    const float* Wend = (const float*)d_in[9];
    const float* bend = (const float*)d_in[10];

    const int* src = ei;        // edge_index[0]
    const int* dst = ei + NE;   // edge_index[1]

    float* gsum      = (float*)d_ws;
    float* gcnt      = (float*)d_ws + NG;
    int*   blockCnt  = (int*)d_ws + 2 * NG;
    int*   bucketTot = blockCnt + (size_t)NBLKE * NBUCK;
    int*   bucketBase= bucketTot + NBUCK;
    int*   offs      = bucketBase + NBUCK + 1;
    size_t po        = (size_t)(offs - (int*)d_ws) + NN + 1;
    po               = (po + 3) & ~(size_t)3;            // 16B align
    int*   pairs     = (int*)d_ws + po;
    int*   csr       = pairs + NE;
    uint*  h1u       = (uint*)(csr + NE);

    // zero only gsum/gcnt (everything else fully rewritten each launch)
    hipMemsetAsync(d_ws, 0, 2 * NG * sizeof(float), stream);

    k_bhist     <<<NBLKE, 512, 0, stream>>>(dst, blockCnt);
    k_bucketscan<<<NBUCK, 512, 0, stream>>>(blockCnt, bucketTot);
    k_basescan  <<<1, 512, 0, stream>>>(bucketTot, bucketBase, offs);
    k_bscatter  <<<NBLKE, 512, 0, stream>>>(src, dst, blockCnt, bucketBase, pairs);
    k_fill2c1   <<<NBUCK, 512, 0, stream>>>(bucketBase, pairs, x, W1l, b1l, W1r,
                                            offs, csr, h1u);
    k_conv2pool <<<NN / 32, 256, 0, stream>>>(offs, csr, h1u, W2l, b2l, W2r,
                                              Wend, bend, batch, gsum, gcnt);
    k_final     <<<1, 64, 0, stream>>>(gsum, gcnt, (float*)d_out);
}

// Round 5
// 122.825 us; speedup vs baseline: 9.1303x; 1.1750x over previous
//
#include <hip/hip_runtime.h>
#include <math.h>

#define NN 100000     // nodes
#define NE 3200000    // edges
#define NG 64         // graphs
#define HID 16
#define EPB 8192                          // edges per block in bucket pipeline
#define NBLKE ((NE + EPB - 1) / EPB)      // 391 edge blocks
#define NBUCK ((NN + 255) / 256)          // 391 buckets (256 nodes each)
#define LMAX 10240                        // per-bucket LDS sorted-src capacity

typedef unsigned int uint;

// ---------------- workspace layout (4-byte units) ----------------
// gsum      [0, NG)                     float  } zeroed each launch
// gcnt      [NG, 2NG)                   float  } zeroed each launch
// blockCnt  [2NG, +NBLKE*NBUCK)         int
// bucketTot [.., +NBUCK)                int
// bucketBase[.., +NBUCK+1)              int
// offs      [.., +NN+1)                 int    (node CSR offsets; [NN]=NE sentinel)
// pad to 16B
// pairs     [.., +NE)                   int    ((src<<8)|dst_low8, bucket-sorted)
// csr       [.., +NE)                   int    (src ids grouped by dst)
// h1u       [.., +8*NN)                 uint   (h1 relu'd, bf16x2 packed, 32B/row)

__device__ inline uint bf16pair(float a, float b) {
    uint ua = __float_as_uint(a), ub = __float_as_uint(b);
    ua = (ua + 0x7fffu + ((ua >> 16) & 1u)) >> 16;
    ub = (ub + 0x7fffu + ((ub >> 16) & 1u)) >> 16;
    return ua | (ub << 16);
}

__global__ __launch_bounds__(512) void k_bhist(const int* __restrict__ dst,
                                               int* __restrict__ blockCnt) {
    __shared__ int h[NBUCK];
    int t = threadIdx.x;
    for (int i = t; i < NBUCK; i += 512) h[i] = 0;
    __syncthreads();
    int base = blockIdx.x * EPB;
    int n4 = (min(base + EPB, NE) - base) >> 2;       // always divisible by 4
    const int4* d4 = (const int4*)(dst + base);
    for (int i = t; i < n4; i += 512) {
        int4 v = d4[i];
        atomicAdd(&h[v.x >> 8], 1);
        atomicAdd(&h[v.y >> 8], 1);
        atomicAdd(&h[v.z >> 8], 1);
        atomicAdd(&h[v.w >> 8], 1);
    }
    __syncthreads();
    for (int i = t; i < NBUCK; i += 512)
        blockCnt[blockIdx.x * NBUCK + i] = h[i];
}

// per-bucket: exclusive prefix over the 391 edge-blocks (in place) + bucket total
__global__ __launch_bounds__(512) void k_bucketscan(int* __restrict__ blockCnt,
                                                    int* __restrict__ bucketTot) {
    __shared__ int a[512];
    int t = threadIdx.x, b = blockIdx.x;
    a[t] = (t < NBLKE) ? blockCnt[t * NBUCK + b] : 0;
    __syncthreads();
    for (int off = 1; off < 512; off <<= 1) {
        int x = a[t] + ((t >= off) ? a[t - off] : 0);
        __syncthreads();
        a[t] = x;
        __syncthreads();
    }
    if (t < NBLKE) blockCnt[t * NBUCK + b] = (t ? a[t - 1] : 0);
    if (t == 0) bucketTot[b] = a[511];
}

// exclusive scan of bucket totals -> bucketBase; sentinel offs[NN]=NE
__global__ __launch_bounds__(512) void k_basescan(const int* __restrict__ bucketTot,
                                                  int* __restrict__ bucketBase,
                                                  int* __restrict__ offs) {
    __shared__ int a[512];
    int t = threadIdx.x;
    a[t] = (t < NBUCK) ? bucketTot[t] : 0;
    __syncthreads();
    for (int off = 1; off < 512; off <<= 1) {
        int x = a[t] + ((t >= off) ? a[t - off] : 0);
        __syncthreads();
        a[t] = x;
        __syncthreads();
    }
    if (t < NBUCK) bucketBase[t] = (t ? a[t - 1] : 0);
    if (t == 0) { bucketBase[NBUCK] = a[511]; offs[NN] = a[511]; }
}

// scatter packed (src<<8 | dst&255) into bucket-partitioned pairs array
__global__ __launch_bounds__(512) void k_bscatter(const int* __restrict__ src,
                                                  const int* __restrict__ dst,
                                                  const int* __restrict__ blockCnt,
                                                  const int* __restrict__ bucketBase,
                                                  int* __restrict__ pairs) {
    __shared__ int cur[NBUCK];
    int t = threadIdx.x;
    for (int i = t; i < NBUCK; i += 512)
        cur[i] = blockCnt[blockIdx.x * NBUCK + i] + bucketBase[i];
    __syncthreads();
    int base = blockIdx.x * EPB;
    int n4 = (min(base + EPB, NE) - base) >> 2;
    const int4* d4 = (const int4*)(dst + base);
    const int4* s4 = (const int4*)(src + base);
    for (int i = t; i < n4; i += 512) {
        int4 dv = d4[i];
        int4 sv = s4[i];
        int p0 = atomicAdd(&cur[dv.x >> 8], 1);
        pairs[p0] = (sv.x << 8) | (dv.x & 255);
        int p1 = atomicAdd(&cur[dv.y >> 8], 1);
        pairs[p1] = (sv.y << 8) | (dv.y & 255);
        int p2 = atomicAdd(&cur[dv.z >> 8], 1);
        pairs[p2] = (sv.z << 8) | (dv.z & 255);
        int p3 = atomicAdd(&cur[dv.w >> 8], 1);
        pairs[p3] = (sv.w << 8) | (dv.w & 255);
    }
}

// one block per bucket: node hist+scan -> offs; csr fill (sorted srcs also kept
// in LDS); fused conv1 as per-node LDS segment sum + x gather + GEMV + bf16 store.
__global__ __launch_bounds__(512) void k_fill2c1(
    const int* __restrict__ bucketBase, const int* __restrict__ pairs,
    const float* __restrict__ x,
    const float* __restrict__ W1l, const float* __restrict__ b1l,
    const float* __restrict__ W1r,
    int* __restrict__ offs, int* __restrict__ csr, uint* __restrict__ h1u) {
    __shared__ int a[256];
    __shared__ int lcur[256];
    __shared__ int lss[LMAX];
    int t = threadIdx.x, b = blockIdx.x;
    int pb = bucketBase[b], pe = bucketBase[b + 1];
    if (t < 256) a[t] = 0;
    __syncthreads();
    for (int e = pb + t; e < pe; e += 512)
        atomicAdd(&a[pairs[e] & 255], 1);
    __syncthreads();
    for (int off = 1; off < 256; off <<= 1) {
        int v = 0;
        if (t < 256) v = a[t] + ((t >= off) ? a[t - off] : 0);
        __syncthreads();
        if (t < 256) a[t] = v;
        __syncthreads();
    }
    if (t < 256) lcur[t] = t ? a[t - 1] : 0;    // bucket-local cursor
    __syncthreads();
    for (int e = pb + t; e < pe; e += 512) {
        int v = pairs[e];
        int s = v >> 8, dl = v & 255;
        int lpos = atomicAdd(&lcur[dl], 1);
        csr[pb + lpos] = s;
        if (lpos < LMAX) lss[lpos] = s;
    }
    __syncthreads();
    if (t < 256) {
        int node = b * 256 + t;
        if (node < NN) {
            int excl = t ? a[t - 1] : 0;
            int cntn = a[t] - excl;
            offs[node] = pb + excl;
            float s0 = 0.f, s1 = 0.f;
            for (int k = 0; k < cntn; ++k) {
                int idx = excl + k;
                int s = (idx < LMAX) ? lss[idx] : csr[pb + idx];
                float2 xv = *(const float2*)(x + 2 * s);
                s0 += xv.x; s1 += xv.y;
            }
            float inv = 1.0f / fmaxf((float)cntn, 1.0f);
            float m0 = s0 * inv, m1 = s1 * inv;
            float x0 = x[2 * node], x1 = x[2 * node + 1];
            float o[16];
#pragma unroll
            for (int h = 0; h < 16; ++h)
                o[h] = fmaxf(m0 * W1l[h] + m1 * W1l[16 + h] + b1l[h]
                           + x0 * W1r[h] + x1 * W1r[16 + h], 0.f);
            uint4 o0, o1;
            o0.x = bf16pair(o[0], o[1]);   o0.y = bf16pair(o[2], o[3]);
            o0.z = bf16pair(o[4], o[5]);   o0.w = bf16pair(o[6], o[7]);
            o1.x = bf16pair(o[8], o[9]);   o1.y = bf16pair(o[10], o[11]);
            o1.z = bf16pair(o[12], o[13]); o1.w = bf16pair(o[14], o[15]);
            uint4* d4 = (uint4*)(h1u + (size_t)node * 8);
            d4[0] = o0; d4[1] = o1;
        }
    }
}

// conv2 + head + pool. 8 lanes/node, 32 nodes/block.
__global__ __launch_bounds__(256) void k_conv2pool(
    const int* __restrict__ offs, const int* __restrict__ csr,
    const uint* __restrict__ h1u,
    const float* __restrict__ W2l, const float* __restrict__ b2l,
    const float* __restrict__ W2r, const float* __restrict__ Wend,
    const float* __restrict__ bend, const int* __restrict__ batch,
    float* __restrict__ gsum, float* __restrict__ gcnt) {
    __shared__ float sWl[256], sWr[256], sB[HID], sWe[HID];
    __shared__ float sm[32][17], shr[32][17];
    __shared__ float ls[NG], lc[NG];
    int t = threadIdx.x;
    sWl[t] = W2l[t];
    sWr[t] = W2r[t];
    if (t < HID) { sB[t] = b2l[t]; sWe[t] = Wend[t]; }
    if (t < NG) { ls[t] = 0.f; lc[t] = 0.f; }

    int g = t >> 3;              // node slot 0..31
    int l8 = t & 7;
    int gbase = (t & 63) & 56;   // wave-relative base lane of 8-lane group
    int i = blockIdx.x * 32 + g; // 3125*32 == NN exactly
    int beg = offs[i], end = offs[i + 1];
    float acc0 = 0.f, acc1 = 0.f;
    int kb = beg;
    for (; kb + 8 <= end; kb += 8) {
        int sv = csr[kb + l8];
#pragma unroll
        for (int j = 0; j < 8; ++j) {
            int s = __shfl(sv, gbase + j, 64);
            uint u = h1u[(size_t)s * 8 + l8];
            acc0 += __uint_as_float(u << 16);
            acc1 += __uint_as_float(u & 0xffff0000u);
        }
    }
    if (kb < end) {
        int idx = kb + l8;
        int sv = (idx < end) ? csr[idx] : 0;
        int nb = end - kb;
        for (int j = 0; j < nb; ++j) {
            int s = __shfl(sv, gbase + j, 64);
            uint u = h1u[(size_t)s * 8 + l8];
            acc0 += __uint_as_float(u << 16);
            acc1 += __uint_as_float(u & 0xffff0000u);
        }
    }
    float inv = 1.0f / fmaxf((float)(end - beg), 1.0f);
    uint us = h1u[(size_t)i * 8 + l8];
    sm[g][2 * l8]      = acc0 * inv;
    sm[g][2 * l8 + 1]  = acc1 * inv;
    shr[g][2 * l8]     = __uint_as_float(us << 16);
    shr[g][2 * l8 + 1] = __uint_as_float(us & 0xffff0000u);
    __syncthreads();

    int h0 = l8, h1 = l8 + 8;
    float a0 = sB[h0], a1 = sB[h1];
#pragma unroll
    for (int ff = 0; ff < HID; ++ff) {
        float m = sm[g][ff], r = shr[g][ff];
        a0 += m * sWl[ff * HID + h0] + r * sWr[ff * HID + h0];
        a1 += m * sWl[ff * HID + h1] + r * sWr[ff * HID + h1];
    }
    float y = fmaxf(a0, 0.f) * sWe[h0] + fmaxf(a1, 0.f) * sWe[h1];
    y += __shfl_xor(y, 1, 64);
    y += __shfl_xor(y, 2, 64);
    y += __shfl_xor(y, 4, 64);
    if (l8 == 0) {
        int bg = batch[i];
        atomicAdd(&ls[bg], y + bend[0]);
        atomicAdd(&lc[bg], 1.0f);
    }
    __syncthreads();
    if (t < NG && lc[t] != 0.0f) {
        unsafeAtomicAdd(&gsum[t], ls[t]);
        unsafeAtomicAdd(&gcnt[t], lc[t]);
    }
}

__global__ void k_final(const float* __restrict__ gsum, const float* __restrict__ gcnt,
                        float* __restrict__ out) {
    int g = threadIdx.x;
    if (g < NG) {
        float p = gsum[g] / fmaxf(gcnt[g], 1.0f);
        out[g] = 1.0f / (1.0f + expf(-p));
    }
}

extern "C" void kernel_launch(void* const* d_in, const int* in_sizes, int n_in,
                              void* d_out, int out_size, void* d_ws, size_t ws_size,
                              hipStream_t stream) {
    const float* x    = (const float*)d_in[0];
    const int*   ei   = (const int*)d_in[1];
    const int*   batch= (const int*)d_in[2];
    const float* W1l  = (const float*)d_in[3];
    const float* b1l  = (const float*)d_in[4];
    const float* W1r  = (const float*)d_in[5];
    const float* W2l  = (const float*)d_in[6];
    const float* b2l  = (const float*)d_in[7];
    const float* W2r  = (const float*)d_in[8];
    const float* Wend = (const float*)d_in[9];
    const float* bend = (const float*)d_in[10];

    const int* src = ei;        // edge_index[0]
    const int* dst = ei + NE;   // edge_index[1]

    float* gsum      = (float*)d_ws;
    float* gcnt      = (float*)d_ws + NG;
    int*   blockCnt  = (int*)d_ws + 2 * NG;
    int*   bucketTot = blockCnt + (size_t)NBLKE * NBUCK;
    int*   bucketBase= bucketTot + NBUCK;
    int*   offs      = bucketBase + NBUCK + 1;
    size_t po        = (size_t)(offs - (int*)d_ws) + NN + 1;
    po               = (po + 3) & ~(size_t)3;            // 16B align
    int*   pairs     = (int*)d_ws + po;
    int*   csr       = pairs + NE;
    uint*  h1u       = (uint*)(csr + NE);

    // zero only gsum/gcnt (everything else fully rewritten each launch)
    hipMemsetAsync(d_ws, 0, 2 * NG * sizeof(float), stream);

    k_bhist     <<<NBLKE, 512, 0, stream>>>(dst, blockCnt);
    k_bucketscan<<<NBUCK, 512, 0, stream>>>(blockCnt, bucketTot);
    k_basescan  <<<1, 512, 0, stream>>>(bucketTot, bucketBase, offs);
    k_bscatter  <<<NBLKE, 512, 0, stream>>>(src, dst, blockCnt, bucketBase, pairs);
    k_fill2c1   <<<NBUCK, 512, 0, stream>>>(bucketBase, pairs, x, W1l, b1l, W1r,
                                            offs, csr, h1u);
    k_conv2pool <<<NN / 32, 256, 0, stream>>>(offs, csr, h1u, W2l, b2l, W2r,
                                              Wend, bend, batch, gsum, gcnt);
    k_final     <<<1, 64, 0, stream>>>(gsum, gcnt, (float*)d_out);
}

// Round 6
// 117.242 us; speedup vs baseline: 9.5651x; 1.0476x over previous
//
#include <hip/hip_runtime.h>
#include <math.h>

#define NN 100000     // nodes
#define NE 3200000    // edges
#define NG 64         // graphs
#define HID 16
#define EPB 8192                          // edges per block in bucket pipeline
#define NBLKE ((NE + EPB - 1) / EPB)      // 391 edge blocks
#define NBUCK ((NN + 255) / 256)          // 391 buckets (256 nodes each)
#define LMAX 10240                        // per-bucket LDS sorted-src capacity

typedef unsigned int uint;

// ---------------- workspace layout (4-byte units) ----------------
// gsum      [0, NG)                     float  (zeroed by k_basescan)
// gcnt      [NG, 2NG)                   float  (zeroed by k_basescan)
// blockCnt  [2NG, +NBUCK*NBLKE)         int    (layout [bucket][blk])
// bucketTot [.., +NBUCK)                int
// bucketBase[.., +NBUCK+1)              int
// offs      [.., +NN+1)                 int    (node CSR offsets; [NN]=NE sentinel)
// pad to 16B
// pairs     [.., +NE)                   int    ((src<<8)|dst_low8, bucket-sorted)
// csr       [.., +NE)                   int    (src ids grouped by dst)
// h1u       [.., +8*NN)                 uint   (h1 relu'd, bf16x2 packed, 32B/row)

__device__ inline uint bf16pair(float a, float b) {
    uint ua = __float_as_uint(a), ub = __float_as_uint(b);
    ua = (ua + 0x7fffu + ((ua >> 16) & 1u)) >> 16;
    ub = (ub + 0x7fffu + ((ub >> 16) & 1u)) >> 16;
    return ua | (ub << 16);
}

__global__ __launch_bounds__(512) void k_bhist(const int* __restrict__ dst,
                                               int* __restrict__ blockCnt) {
    __shared__ int h[NBUCK];
    int t = threadIdx.x;
    for (int i = t; i < NBUCK; i += 512) h[i] = 0;
    __syncthreads();
    int base = blockIdx.x * EPB;
    int n4 = (min(base + EPB, NE) - base) >> 2;       // always divisible by 4
    const int4* d4 = (const int4*)(dst + base);
    for (int i = t; i < n4; i += 512) {
        int4 v = d4[i];
        atomicAdd(&h[v.x >> 8], 1);
        atomicAdd(&h[v.y >> 8], 1);
        atomicAdd(&h[v.z >> 8], 1);
        atomicAdd(&h[v.w >> 8], 1);
    }
    __syncthreads();
    for (int i = t; i < NBUCK; i += 512)
        blockCnt[i * NBLKE + blockIdx.x] = h[i];       // [bucket][blk]
}

// per-bucket: exclusive prefix over the 391 edge-blocks (in place) + bucket total
__global__ __launch_bounds__(512) void k_bucketscan(int* __restrict__ blockCnt,
                                                    int* __restrict__ bucketTot) {
    __shared__ int a[512];
    int t = threadIdx.x, b = blockIdx.x;
    a[t] = (t < NBLKE) ? blockCnt[b * NBLKE + t] : 0;  // coalesced
    __syncthreads();
    for (int off = 1; off < 512; off <<= 1) {
        int x = a[t] + ((t >= off) ? a[t - off] : 0);
        __syncthreads();
        a[t] = x;
        __syncthreads();
    }
    if (t < NBLKE) blockCnt[b * NBLKE + t] = (t ? a[t - 1] : 0);
    if (t == 0) bucketTot[b] = a[511];
}

// exclusive scan of bucket totals -> bucketBase; sentinel offs[NN]=NE;
// also zeroes gsum/gcnt (replaces the hipMemsetAsync dispatch)
__global__ __launch_bounds__(512) void k_basescan(const int* __restrict__ bucketTot,
                                                  int* __restrict__ bucketBase,
                                                  int* __restrict__ offs,
                                                  float* __restrict__ gsum,
                                                  float* __restrict__ gcnt) {
    __shared__ int a[512];
    int t = threadIdx.x;
    if (t < NG) { gsum[t] = 0.f; gcnt[t] = 0.f; }
    a[t] = (t < NBUCK) ? bucketTot[t] : 0;
    __syncthreads();
    for (int off = 1; off < 512; off <<= 1) {
        int x = a[t] + ((t >= off) ? a[t - off] : 0);
        __syncthreads();
        a[t] = x;
        __syncthreads();
    }
    if (t < NBUCK) bucketBase[t] = (t ? a[t - 1] : 0);
    if (t == 0) { bucketBase[NBUCK] = a[511]; offs[NN] = a[511]; }
}

// scatter packed (src<<8 | dst&255) into bucket-partitioned pairs array
__global__ __launch_bounds__(512) void k_bscatter(const int* __restrict__ src,
                                                  const int* __restrict__ dst,
                                                  const int* __restrict__ blockCnt,
                                                  const int* __restrict__ bucketBase,
                                                  int* __restrict__ pairs) {
    __shared__ int cur[NBUCK];
    int t = threadIdx.x;
    for (int i = t; i < NBUCK; i += 512)
        cur[i] = blockCnt[i * NBLKE + blockIdx.x] + bucketBase[i];
    __syncthreads();
    int base = blockIdx.x * EPB;
    int n4 = (min(base + EPB, NE) - base) >> 2;
    const int4* d4 = (const int4*)(dst + base);
    const int4* s4 = (const int4*)(src + base);
    for (int i = t; i < n4; i += 512) {
        int4 dv = d4[i];
        int4 sv = s4[i];
        int p0 = atomicAdd(&cur[dv.x >> 8], 1);
        pairs[p0] = (sv.x << 8) | (dv.x & 255);
        int p1 = atomicAdd(&cur[dv.y >> 8], 1);
        pairs[p1] = (sv.y << 8) | (dv.y & 255);
        int p2 = atomicAdd(&cur[dv.z >> 8], 1);
        pairs[p2] = (sv.z << 8) | (dv.z & 255);
        int p3 = atomicAdd(&cur[dv.w >> 8], 1);
        pairs[p3] = (sv.w << 8) | (dv.w & 255);
    }
}

// one block per bucket: node hist+scan -> offs; csr fill (sorted srcs also kept
// in LDS); fused conv1 as per-node LDS segment sum + x gather + GEMV + bf16 store.
__global__ __launch_bounds__(512) void k_fill2c1(
    const int* __restrict__ bucketBase, const int* __restrict__ pairs,
    const float* __restrict__ x,
    const float* __restrict__ W1l, const float* __restrict__ b1l,
    const float* __restrict__ W1r,
    int* __restrict__ offs, int* __restrict__ csr, uint* __restrict__ h1u) {
    __shared__ int a[256];
    __shared__ int lcur[256];
    __shared__ int lss[LMAX];
    int t = threadIdx.x, b = blockIdx.x;
    int pb = bucketBase[b], pe = bucketBase[b + 1];
    if (t < 256) a[t] = 0;
    __syncthreads();
    for (int e = pb + t; e < pe; e += 512)
        atomicAdd(&a[pairs[e] & 255], 1);
    __syncthreads();
    for (int off = 1; off < 256; off <<= 1) {
        int v = 0;
        if (t < 256) v = a[t] + ((t >= off) ? a[t - off] : 0);
        __syncthreads();
        if (t < 256) a[t] = v;
        __syncthreads();
    }
    if (t < 256) lcur[t] = t ? a[t - 1] : 0;    // bucket-local cursor
    __syncthreads();
    for (int e = pb + t; e < pe; e += 512) {
        int v = pairs[e];
        int s = v >> 8, dl = v & 255;
        int lpos = atomicAdd(&lcur[dl], 1);
        csr[pb + lpos] = s;
        if (lpos < LMAX) lss[lpos] = s;
    }
    __syncthreads();
    if (t < 256) {
        int node = b * 256 + t;
        if (node < NN) {
            int excl = t ? a[t - 1] : 0;
            int cntn = a[t] - excl;
            offs[node] = pb + excl;
            float s0 = 0.f, s1 = 0.f;
            for (int k = 0; k < cntn; ++k) {
                int idx = excl + k;
                int s = (idx < LMAX) ? lss[idx] : csr[pb + idx];
                float2 xv = *(const float2*)(x + 2 * s);
                s0 += xv.x; s1 += xv.y;
            }
            float inv = 1.0f / fmaxf((float)cntn, 1.0f);
            float m0 = s0 * inv, m1 = s1 * inv;
            float x0 = x[2 * node], x1 = x[2 * node + 1];
            float o[16];
#pragma unroll
            for (int h = 0; h < 16; ++h)
                o[h] = fmaxf(m0 * W1l[h] + m1 * W1l[16 + h] + b1l[h]
                           + x0 * W1r[h] + x1 * W1r[16 + h], 0.f);
            uint4 o0, o1;
            o0.x = bf16pair(o[0], o[1]);   o0.y = bf16pair(o[2], o[3]);
            o0.z = bf16pair(o[4], o[5]);   o0.w = bf16pair(o[6], o[7]);
            o1.x = bf16pair(o[8], o[9]);   o1.y = bf16pair(o[10], o[11]);
            o1.z = bf16pair(o[12], o[13]); o1.w = bf16pair(o[14], o[15]);
            uint4* d4 = (uint4*)(h1u + (size_t)node * 8);
            d4[0] = o0; d4[1] = o1;
        }
    }
}

// conv2 + head + pool. 8 lanes/node, 32 nodes/block.
// 16 independent h1u row-gathers buffered in registers per iteration.
__global__ __launch_bounds__(256) void k_conv2pool(
    const int* __restrict__ offs, const int* __restrict__ csr,
    const uint* __restrict__ h1u,
    const float* __restrict__ W2l, const float* __restrict__ b2l,
    const float* __restrict__ W2r, const float* __restrict__ Wend,
    const float* __restrict__ bend, const int* __restrict__ batch,
    float* __restrict__ gsum, float* __restrict__ gcnt) {
    __shared__ float sWl[256], sWr[256], sB[HID], sWe[HID];
    __shared__ float sm[32][17], shr[32][17];
    __shared__ float ls[NG], lc[NG];
    int t = threadIdx.x;
    sWl[t] = W2l[t];
    sWr[t] = W2r[t];
    if (t < HID) { sB[t] = b2l[t]; sWe[t] = Wend[t]; }
    if (t < NG) { ls[t] = 0.f; lc[t] = 0.f; }

    int g = t >> 3;              // node slot 0..31
    int l8 = t & 7;
    int gbase = (t & 63) & 56;   // wave-relative base lane of 8-lane group
    int i = blockIdx.x * 32 + g; // 3125*32 == NN exactly
    int beg = offs[i], end = offs[i + 1];
    float acc0 = 0.f, acc1 = 0.f;
    int kb = beg;
    uint ubuf[16];
    // 16-deep pipelined main loop
    for (; kb + 16 <= end; kb += 16) {
        int sv0 = csr[kb + l8];
        int sv1 = csr[kb + 8 + l8];
#pragma unroll
        for (int j = 0; j < 8; ++j) {
            int s = __shfl(sv0, gbase + j, 64);
            ubuf[j] = h1u[(size_t)s * 8 + l8];
        }
#pragma unroll
        for (int j = 0; j < 8; ++j) {
            int s = __shfl(sv1, gbase + j, 64);
            ubuf[8 + j] = h1u[(size_t)s * 8 + l8];
        }
#pragma unroll
        for (int j = 0; j < 16; ++j) {
            acc0 += __uint_as_float(ubuf[j] << 16);
            acc1 += __uint_as_float(ubuf[j] & 0xffff0000u);
        }
    }
    // 8-deep
    for (; kb + 8 <= end; kb += 8) {
        int sv = csr[kb + l8];
#pragma unroll
        for (int j = 0; j < 8; ++j) {
            int s = __shfl(sv, gbase + j, 64);
            ubuf[j] = h1u[(size_t)s * 8 + l8];
        }
#pragma unroll
        for (int j = 0; j < 8; ++j) {
            acc0 += __uint_as_float(ubuf[j] << 16);
            acc1 += __uint_as_float(ubuf[j] & 0xffff0000u);
        }
    }
    // scalar tail
    if (kb < end) {
        int idx = kb + l8;
        int sv = (idx < end) ? csr[idx] : 0;
        int nb = end - kb;
        for (int j = 0; j < nb; ++j) {
            int s = __shfl(sv, gbase + j, 64);
            uint u = h1u[(size_t)s * 8 + l8];
            acc0 += __uint_as_float(u << 16);
            acc1 += __uint_as_float(u & 0xffff0000u);
        }
    }
    float inv = 1.0f / fmaxf((float)(end - beg), 1.0f);
    uint us = h1u[(size_t)i * 8 + l8];
    sm[g][2 * l8]      = acc0 * inv;
    sm[g][2 * l8 + 1]  = acc1 * inv;
    shr[g][2 * l8]     = __uint_as_float(us << 16);
    shr[g][2 * l8 + 1] = __uint_as_float(us & 0xffff0000u);
    __syncthreads();

    int h0 = l8, h1 = l8 + 8;
    float a0 = sB[h0], a1 = sB[h1];
#pragma unroll
    for (int ff = 0; ff < HID; ++ff) {
        float m = sm[g][ff], r = shr[g][ff];
        a0 += m * sWl[ff * HID + h0] + r * sWr[ff * HID + h0];
        a1 += m * sWl[ff * HID + h1] + r * sWr[ff * HID + h1];
    }
    float y = fmaxf(a0, 0.f) * sWe[h0] + fmaxf(a1, 0.f) * sWe[h1];
    y += __shfl_xor(y, 1, 64);
    y += __shfl_xor(y, 2, 64);
    y += __shfl_xor(y, 4, 64);
    if (l8 == 0) {
        int bg = batch[i];
        atomicAdd(&ls[bg], y + bend[0]);
        atomicAdd(&lc[bg], 1.0f);
    }
    __syncthreads();
    if (t < NG && lc[t] != 0.0f) {
        unsafeAtomicAdd(&gsum[t], ls[t]);
        unsafeAtomicAdd(&gcnt[t], lc[t]);
    }
}

__global__ void k_final(const float* __restrict__ gsum, const float* __restrict__ gcnt,
                        float* __restrict__ out) {
    int g = threadIdx.x;
    if (g < NG) {
        float p = gsum[g] / fmaxf(gcnt[g], 1.0f);
        out[g] = 1.0f / (1.0f + expf(-p));
    }
}

extern "C" void kernel_launch(void* const* d_in, const int* in_sizes, int n_in,
                              void* d_out, int out_size, void* d_ws, size_t ws_size,
                              hipStream_t stream) {
    const float* x    = (const float*)d_in[0];
    const int*   ei   = (const int*)d_in[1];
    const int*   batch= (const int*)d_in[2];
    const float* W1l  = (const float*)d_in[3];
    const float* b1l  = (const float*)d_in[4];
    const float* W1r  = (const float*)d_in[5];
    const float* W2l  = (const float*)d_in[6];
    const float* b2l  = (const float*)d_in[7];
    const float* W2r  = (const float*)d_in[8];
    const float* Wend = (const float*)d_in[9];
    const float* bend = (const float*)d_in[10];

    const int* src = ei;        // edge_index[0]
    const int* dst = ei + NE;   // edge_index[1]

    float* gsum      = (float*)d_ws;
    float* gcnt      = (float*)d_ws + NG;
    int*   blockCnt  = (int*)d_ws + 2 * NG;
    int*   bucketTot = blockCnt + (size_t)NBLKE * NBUCK;
    int*   bucketBase= bucketTot + NBUCK;
    int*   offs      = bucketBase + NBUCK + 1;
    size_t po        = (size_t)(offs - (int*)d_ws) + NN + 1;
    po               = (po + 3) & ~(size_t)3;            // 16B align
    int*   pairs     = (int*)d_ws + po;
    int*   csr       = pairs + NE;
    uint*  h1u       = (uint*)(csr + NE);

    k_bhist     <<<NBLKE, 512, 0, stream>>>(dst, blockCnt);
    k_bucketscan<<<NBUCK, 512, 0, stream>>>(blockCnt, bucketTot);
    k_basescan  <<<1, 512, 0, stream>>>(bucketTot, bucketBase, offs, gsum, gcnt);
    k_bscatter  <<<NBLKE, 512, 0, stream>>>(src, dst, blockCnt, bucketBase, pairs);
    k_fill2c1   <<<NBUCK, 512, 0, stream>>>(bucketBase, pairs, x, W1l, b1l, W1r,
                                            offs, csr, h1u);
    k_conv2pool <<<NN / 32, 256, 0, stream>>>(offs, csr, h1u, W2l, b2l, W2r,
                                              Wend, bend, batch, gsum, gcnt);
    k_final     <<<1, 64, 0, stream>>>(gsum, gcnt, (float*)d_out);
}

// Round 8
// 105.454 us; speedup vs baseline: 10.6343x; 1.1118x over previous
//
#include <hip/hip_runtime.h>
#include <math.h>

#define NN 100000     // nodes
#define NE 3200000    // edges
#define NG 64         // graphs
#define HID 16
#define EPB 8192                          // edges per block in bucket pipeline
#define NBLKE ((NE + EPB - 1) / EPB)      // 391 edge blocks
#define NBUCK ((NN + 255) / 256)          // 391 buckets (256 nodes each)
#define LMAX 10240                        // per-bucket LDS sorted-src capacity

typedef unsigned int uint;
typedef float vf2 __attribute__((ext_vector_type(2)));

// ---------------- workspace layout (4-byte units) ----------------
// gsum      [0, NG)                     float  (zeroed by k_basescan)
// gcnt      [NG, 2NG)                   float  (zeroed by k_basescan)
// blockCnt  [2NG, +NBUCK*NBLKE)         int    (layout [bucket][blk])
// bucketTot [.., +NBUCK)                int
// bucketBase[.., +NBUCK+1)              int
// offs      [.., +NN+1)                 int    (node CSR offsets; [NN]=NE sentinel)
// pad to 16B
// pairs     [.., +NE)                   int    ((src<<8)|dst_low8, bucket-sorted)
// csr       [.., +NE)                   int    (src ids grouped by dst)
// h8        [.., +4*NN)                 uint   (h1 relu'd, fp8 e4m3 x16, 16B/row)

// ---------- fp8 e4m3 helpers (HW builtins; word-select must be literal) ----------
template <bool HI>
__device__ inline vf2 dec2fp8(uint u) {
#if __has_builtin(__builtin_amdgcn_cvt_pk_f32_fp8)
    return __builtin_amdgcn_cvt_pk_f32_fp8((int)u, HI);
#else
    vf2 r;
    uint b0 = (u >> (HI ? 16 : 0)) & 0xff;
    uint b1 = (u >> (HI ? 24 : 8)) & 0xff;
    uint em0 = b0 & 0x7f, em1 = b1 & 0x7f;
    float v0 = (em0 >= 8) ? __uint_as_float(((em0 >> 3) + 120) << 23 | (em0 & 7) << 20)
                          : (float)em0 * 0.001953125f;
    float v1 = (em1 >= 8) ? __uint_as_float(((em1 >> 3) + 120) << 23 | (em1 & 7) << 20)
                          : (float)em1 * 0.001953125f;
    r.x = (b0 & 0x80) ? -v0 : v0;
    r.y = (b1 & 0x80) ? -v1 : v1;
    return r;
#endif
}

__device__ inline uint enc1fp8(float f) {   // f >= 0 (post-relu)
    if (!(f > 0.f)) return 0u;
    f = fminf(f, 448.f);
    uint b = __float_as_uint(f);
    int e = (int)(b >> 23) - 127;
    if (e >= -6) {
        uint m = b & 0x7fffffu;
        uint r = (m + 0x7ffffu + ((m >> 20) & 1u)) >> 20;   // RNE to 3 bits
        uint code = ((uint)(e + 7) << 3) + r;               // carry ok
        return code > 126u ? 126u : code;
    }
    float t = f * 512.f;
    return (uint)(t + 0.5f);
}

template <bool HI>
__device__ inline uint packfp8x2(float a, float b, uint old) {
#if __has_builtin(__builtin_amdgcn_cvt_pk_fp8_f32)
    return (uint)__builtin_amdgcn_cvt_pk_fp8_f32(a, b, (int)old, HI);
#else
    uint v = enc1fp8(a) | (enc1fp8(b) << 8);
    return HI ? ((old & 0x0000ffffu) | (v << 16)) : ((old & 0xffff0000u) | v);
#endif
}

__global__ __launch_bounds__(512) void k_bhist(const int* __restrict__ dst,
                                               int* __restrict__ blockCnt) {
    __shared__ int h[NBUCK];
    int t = threadIdx.x;
    for (int i = t; i < NBUCK; i += 512) h[i] = 0;
    __syncthreads();
    int base = blockIdx.x * EPB;
    int n4 = (min(base + EPB, NE) - base) >> 2;       // always divisible by 4
    const int4* d4 = (const int4*)(dst + base);
    for (int i = t; i < n4; i += 512) {
        int4 v = d4[i];
        atomicAdd(&h[v.x >> 8], 1);
        atomicAdd(&h[v.y >> 8], 1);
        atomicAdd(&h[v.z >> 8], 1);
        atomicAdd(&h[v.w >> 8], 1);
    }
    __syncthreads();
    for (int i = t; i < NBUCK; i += 512)
        blockCnt[i * NBLKE + blockIdx.x] = h[i];       // [bucket][blk]
}

// per-bucket: exclusive prefix over the 391 edge-blocks (in place) + bucket total
__global__ __launch_bounds__(512) void k_bucketscan(int* __restrict__ blockCnt,
                                                    int* __restrict__ bucketTot) {
    __shared__ int a[512];
    int t = threadIdx.x, b = blockIdx.x;
    a[t] = (t < NBLKE) ? blockCnt[b * NBLKE + t] : 0;  // coalesced
    __syncthreads();
    for (int off = 1; off < 512; off <<= 1) {
        int x = a[t] + ((t >= off) ? a[t - off] : 0);
        __syncthreads();
        a[t] = x;
        __syncthreads();
    }
    if (t < NBLKE) blockCnt[b * NBLKE + t] = (t ? a[t - 1] : 0);
    if (t == 0) bucketTot[b] = a[511];
}

// exclusive scan of bucket totals -> bucketBase; sentinel offs[NN]=NE;
// also zeroes gsum/gcnt (replaces the hipMemsetAsync dispatch)
__global__ __launch_bounds__(512) void k_basescan(const int* __restrict__ bucketTot,
                                                  int* __restrict__ bucketBase,
                                                  int* __restrict__ offs,
                                                  float* __restrict__ gsum,
                                                  float* __restrict__ gcnt) {
    __shared__ int a[512];
    int t = threadIdx.x;
    if (t < NG) { gsum[t] = 0.f; gcnt[t] = 0.f; }
    a[t] = (t < NBUCK) ? bucketTot[t] : 0;
    __syncthreads();
    for (int off = 1; off < 512; off <<= 1) {
        int x = a[t] + ((t >= off) ? a[t - off] : 0);
        __syncthreads();
        a[t] = x;
        __syncthreads();
    }
    if (t < NBUCK) bucketBase[t] = (t ? a[t - 1] : 0);
    if (t == 0) { bucketBase[NBUCK] = a[511]; offs[NN] = a[511]; }
}

// scatter packed (src<<8 | dst&255) into bucket-partitioned pairs array
__global__ __launch_bounds__(512) void k_bscatter(const int* __restrict__ src,
                                                  const int* __restrict__ dst,
                                                  const int* __restrict__ blockCnt,
                                                  const int* __restrict__ bucketBase,
                                                  int* __restrict__ pairs) {
    __shared__ int cur[NBUCK];
    int t = threadIdx.x;
    for (int i = t; i < NBUCK; i += 512)
        cur[i] = blockCnt[i * NBLKE + blockIdx.x] + bucketBase[i];
    __syncthreads();
    int base = blockIdx.x * EPB;
    int n4 = (min(base + EPB, NE) - base) >> 2;
    const int4* d4 = (const int4*)(dst + base);
    const int4* s4 = (const int4*)(src + base);
    for (int i = t; i < n4; i += 512) {
        int4 dv = d4[i];
        int4 sv = s4[i];
        int p0 = atomicAdd(&cur[dv.x >> 8], 1);
        pairs[p0] = (sv.x << 8) | (dv.x & 255);
        int p1 = atomicAdd(&cur[dv.y >> 8], 1);
        pairs[p1] = (sv.y << 8) | (dv.y & 255);
        int p2 = atomicAdd(&cur[dv.z >> 8], 1);
        pairs[p2] = (sv.z << 8) | (dv.z & 255);
        int p3 = atomicAdd(&cur[dv.w >> 8], 1);
        pairs[p3] = (sv.w << 8) | (dv.w & 255);
    }
}

// one block per bucket: node hist+scan -> offs; csr fill (sorted srcs also kept
// in LDS); fused conv1 as per-node LDS segment sum + x gather + GEMV + fp8 store.
__global__ __launch_bounds__(512) void k_fill2c1(
    const int* __restrict__ bucketBase, const int* __restrict__ pairs,
    const float* __restrict__ x,
    const float* __restrict__ W1l, const float* __restrict__ b1l,
    const float* __restrict__ W1r,
    int* __restrict__ offs, int* __restrict__ csr, uint* __restrict__ h8) {
    __shared__ int a[256];
    __shared__ int lcur[256];
    __shared__ int lss[LMAX];
    int t = threadIdx.x, b = blockIdx.x;
    int pb = bucketBase[b], pe = bucketBase[b + 1];
    if (t < 256) a[t] = 0;
    __syncthreads();
    for (int e = pb + t; e < pe; e += 512)
        atomicAdd(&a[pairs[e] & 255], 1);
    __syncthreads();
    for (int off = 1; off < 256; off <<= 1) {
        int v = 0;
        if (t < 256) v = a[t] + ((t >= off) ? a[t - off] : 0);
        __syncthreads();
        if (t < 256) a[t] = v;
        __syncthreads();
    }
    if (t < 256) lcur[t] = t ? a[t - 1] : 0;    // bucket-local cursor
    __syncthreads();
    for (int e = pb + t; e < pe; e += 512) {
        int v = pairs[e];
        int s = v >> 8, dl = v & 255;
        int lpos = atomicAdd(&lcur[dl], 1);
        csr[pb + lpos] = s;
        if (lpos < LMAX) lss[lpos] = s;
    }
    __syncthreads();
    if (t < 256) {
        int node = b * 256 + t;
        if (node < NN) {
            int excl = t ? a[t - 1] : 0;
            int cntn = a[t] - excl;
            offs[node] = pb + excl;
            float s0 = 0.f, s1 = 0.f;
            for (int k = 0; k < cntn; ++k) {
                int idx = excl + k;
                int s = (idx < LMAX) ? lss[idx] : csr[pb + idx];
                float2 xv = *(const float2*)(x + 2 * s);
                s0 += xv.x; s1 += xv.y;
            }
            float inv = 1.0f / fmaxf((float)cntn, 1.0f);
            float m0 = s0 * inv, m1 = s1 * inv;
            float x0 = x[2 * node], x1 = x[2 * node + 1];
            float o[16];
#pragma unroll
            for (int h = 0; h < 16; ++h)
                o[h] = fmaxf(m0 * W1l[h] + m1 * W1l[16 + h] + b1l[h]
                           + x0 * W1r[h] + x1 * W1r[16 + h], 0.f);
            uint4 w;
            w.x = packfp8x2<false>(o[0],  o[1],  0u);
            w.x = packfp8x2<true >(o[2],  o[3],  w.x);
            w.y = packfp8x2<false>(o[4],  o[5],  0u);
            w.y = packfp8x2<true >(o[6],  o[7],  w.y);
            w.z = packfp8x2<false>(o[8],  o[9],  0u);
            w.z = packfp8x2<true >(o[10], o[11], w.z);
            w.w = packfp8x2<false>(o[12], o[13], 0u);
            w.w = packfp8x2<true >(o[14], o[15], w.w);
            *(uint4*)(h8 + (size_t)node * 4) = w;
        }
    }
}

// conv2 + head + pool. 4 lanes/node, 64 nodes/block, fp8 16B rows:
// one 16B segment per edge-gather (16 rows per wave-load instruction).
__global__ __launch_bounds__(256) void k_conv2pool(
    const int* __restrict__ offs, const int* __restrict__ csr,
    const uint* __restrict__ h8,
    const float* __restrict__ W2l, const float* __restrict__ b2l,
    const float* __restrict__ W2r, const float* __restrict__ Wend,
    const float* __restrict__ bend, const int* __restrict__ batch,
    float* __restrict__ gsum, float* __restrict__ gcnt) {
    __shared__ float sWl[256], sWr[256], sB[HID], sWe[HID];
    __shared__ float sm[64][17], shr[64][17];
    __shared__ float ls[NG], lc[NG];
    int t = threadIdx.x;
    sWl[t] = W2l[t];
    sWr[t] = W2r[t];
    if (t < HID) { sB[t] = b2l[t]; sWe[t] = Wend[t]; }
    if (t < NG) { ls[t] = 0.f; lc[t] = 0.f; }

    int g = t >> 2;              // node slot 0..63
    int l4 = t & 3;
    int gbase = (t & 63) & 60;   // wave-relative base lane of 4-lane group
    int i = blockIdx.x * 64 + g;
    int beg = 0, end = 0;
    if (i < NN) { beg = offs[i]; end = offs[i + 1]; }
    float a0 = 0.f, a1 = 0.f, a2 = 0.f, a3 = 0.f;
    int kb = beg;
    uint ub[8];
    for (; kb + 8 <= end; kb += 8) {
        int sv0 = csr[kb + l4];
        int sv1 = csr[kb + 4 + l4];
#pragma unroll
        for (int j = 0; j < 4; ++j) {
            int s = __shfl(sv0, gbase + j, 64);
            ub[j] = h8[(size_t)s * 4 + l4];
        }
#pragma unroll
        for (int j = 0; j < 4; ++j) {
            int s = __shfl(sv1, gbase + j, 64);
            ub[4 + j] = h8[(size_t)s * 4 + l4];
        }
#pragma unroll
        for (int j = 0; j < 8; ++j) {
            vf2 p0 = dec2fp8<false>(ub[j]);
            vf2 p1 = dec2fp8<true >(ub[j]);
            a0 += p0.x; a1 += p0.y; a2 += p1.x; a3 += p1.y;
        }
    }
    for (; kb + 4 <= end; kb += 4) {
        int sv = csr[kb + l4];
#pragma unroll
        for (int j = 0; j < 4; ++j) {
            int s = __shfl(sv, gbase + j, 64);
            ub[j] = h8[(size_t)s * 4 + l4];
        }
#pragma unroll
        for (int j = 0; j < 4; ++j) {
            vf2 p0 = dec2fp8<false>(ub[j]);
            vf2 p1 = dec2fp8<true >(ub[j]);
            a0 += p0.x; a1 += p0.y; a2 += p1.x; a3 += p1.y;
        }
    }
    if (kb < end) {
        int idx = kb + l4;
        int sv = (idx < end) ? csr[idx] : 0;
        int nb = end - kb;
        for (int j = 0; j < nb; ++j) {
            int s = __shfl(sv, gbase + j, 64);
            uint u = h8[(size_t)s * 4 + l4];
            vf2 p0 = dec2fp8<false>(u);
            vf2 p1 = dec2fp8<true >(u);
            a0 += p0.x; a1 += p0.y; a2 += p1.x; a3 += p1.y;
        }
    }
    if (i < NN) {
        float inv = 1.0f / fmaxf((float)(end - beg), 1.0f);
        uint us = h8[(size_t)i * 4 + l4];
        vf2 q0 = dec2fp8<false>(us);
        vf2 q1 = dec2fp8<true >(us);
        sm[g][4 * l4 + 0] = a0 * inv;
        sm[g][4 * l4 + 1] = a1 * inv;
        sm[g][4 * l4 + 2] = a2 * inv;
        sm[g][4 * l4 + 3] = a3 * inv;
        shr[g][4 * l4 + 0] = q0.x;
        shr[g][4 * l4 + 1] = q0.y;
        shr[g][4 * l4 + 2] = q1.x;
        shr[g][4 * l4 + 3] = q1.y;
    }
    __syncthreads();

    float y = 0.f;
    if (i < NN) {
#pragma unroll
        for (int k = 0; k < 4; ++k) {
            int h = 4 * l4 + k;
            float a = sB[h];
#pragma unroll
            for (int f = 0; f < HID; ++f)
                a += sm[g][f] * sWl[f * HID + h] + shr[g][f] * sWr[f * HID + h];
            y += fmaxf(a, 0.f) * sWe[h];
        }
    }
    y += __shfl_xor(y, 1, 64);
    y += __shfl_xor(y, 2, 64);
    if (l4 == 0 && i < NN) {
        int bg = batch[i];
        atomicAdd(&ls[bg], y + bend[0]);
        atomicAdd(&lc[bg], 1.0f);
    }
    __syncthreads();
    if (t < NG && lc[t] != 0.0f) {
        unsafeAtomicAdd(&gsum[t], ls[t]);
        unsafeAtomicAdd(&gcnt[t], lc[t]);
    }
}

__global__ void k_final(const float* __restrict__ gsum, const float* __restrict__ gcnt,
                        float* __restrict__ out) {
    int g = threadIdx.x;
    if (g < NG) {
        float p = gsum[g] / fmaxf(gcnt[g], 1.0f);
        out[g] = 1.0f / (1.0f + expf(-p));
    }
}

extern "C" void kernel_launch(void* const* d_in, const int* in_sizes, int n_in,
                              void* d_out, int out_size, void* d_ws, size_t ws_size,
                              hipStream_t stream) {
    const float* x    = (const float*)d_in[0];
    const int*   ei   = (const int*)d_in[1];
    const int*   batch= (const int*)d_in[2];
    const float* W1l  = (const float*)d_in[3];
    const float* b1l  = (const float*)d_in[4];
    const float* W1r  = (const float*)d_in[5];
    const float* W2l  = (const float*)d_in[6];
    const float* b2l  = (const float*)d_in[7];
    const float* W2r  = (const float*)d_in[8];
    const float* Wend = (const float*)d_in[9];
    const float* bend = (const float*)d_in[10];

    const int* src = ei;        // edge_index[0]
    const int* dst = ei + NE;   // edge_index[1]

    float* gsum      = (float*)d_ws;
    float* gcnt      = (float*)d_ws + NG;
    int*   blockCnt  = (int*)d_ws + 2 * NG;
    int*   bucketTot = blockCnt + (size_t)NBLKE * NBUCK;
    int*   bucketBase= bucketTot + NBUCK;
    int*   offs      = bucketBase + NBUCK + 1;
    size_t po        = (size_t)(offs - (int*)d_ws) + NN + 1;
    po               = (po + 3) & ~(size_t)3;            // 16B align
    int*   pairs     = (int*)d_ws + po;
    int*   csr       = pairs + NE;
    uint*  h8        = (uint*)(csr + NE);

    k_bhist     <<<NBLKE, 512, 0, stream>>>(dst, blockCnt);
    k_bucketscan<<<NBUCK, 512, 0, stream>>>(blockCnt, bucketTot);
    k_basescan  <<<1, 512, 0, stream>>>(bucketTot, bucketBase, offs, gsum, gcnt);
    k_bscatter  <<<NBLKE, 512, 0, stream>>>(src, dst, blockCnt, bucketBase, pairs);
    k_fill2c1   <<<NBUCK, 512, 0, stream>>>(bucketBase, pairs, x, W1l, b1l, W1r,
                                            offs, csr, h8);
    k_conv2pool <<<(NN + 63) / 64, 256, 0, stream>>>(offs, csr, h8, W2l, b2l, W2r,
                                                     Wend, bend, batch, gsum, gcnt);
    k_final     <<<1, 64, 0, stream>>>(gsum, gcnt, (float*)d_out);
}